// Round 1
// baseline (307.208 us; speedup 1.0000x reference)
//
#include <hip/hip_runtime.h>

// ElementsFeatureProcessor: B=16384, N=128.
// TM path (is_tm=1): out[b,n,:24] = concat(relu(feat5 @ W^T + b)[16], TM_emb[map_tm(z)][8]) * mask
// Strategy: 3 threads per element.
//   r=0: outputs 0..7  of the 16-wide matvec
//   r=1: outputs 8..15 of the 16-wide matvec
//   r=2: 8-wide embedding gather
// Each thread writes 2 aligned float4s at out + elem*24 + r*8 -> fully
// coalesced contiguous wave stores (96B/elem covered by 3 consecutive lanes).

__global__ __launch_bounds__(256) void tm_kernel(
    const float* __restrict__ info, const int* __restrict__ mask,
    const float* __restrict__ W, const float* __restrict__ bias,
    const float* __restrict__ TM_emb, float* __restrict__ out, int n_elems)
{
    unsigned int gtid = blockIdx.x * blockDim.x + threadIdx.x;
    unsigned int elem = gtid / 3u;              // compiler emits magic-mul
    unsigned int r = gtid - elem * 3u;
    if (elem >= (unsigned int)n_elems) return;

    float m = (float)mask[elem];                // 0.0 or 1.0
    const float* ei = info + (size_t)elem * 7;

    float res[8];
    if (r < 2u) {
        // masked float features (mask==0 -> features 0, then relu(b)*0 = 0)
        float f0 = ei[0] * m, f1 = ei[1] * m, f2 = ei[2] * m,
              f3 = ei[3] * m, f4 = ei[4] * m;
        int ob = (int)r * 8;
        #pragma unroll
        for (int k = 0; k < 8; ++k) {
            const float* w = W + (size_t)(ob + k) * 5;
            float acc = bias[ob + k];
            acc = fmaf(f0, w[0], acc);
            acc = fmaf(f1, w[1], acc);
            acc = fmaf(f2, w[2], acc);
            acc = fmaf(f3, w[3], acc);
            acc = fmaf(f4, w[4], acc);
            res[k] = fmaxf(acc, 0.0f) * m;
        }
    } else {
        // atomic number: masked z cast to int (exact for z <= 48)
        int z = (int)(ei[5] * m);
        int idx = (z <= 0) ? 0 : ((z <= 30) ? z - 20 : z - 28);
        const float4* e = (const float4*)(TM_emb + (size_t)idx * 8); // 32B aligned rows
        float4 a0 = e[0], a1 = e[1];
        res[0] = a0.x * m; res[1] = a0.y * m; res[2] = a0.z * m; res[3] = a0.w * m;
        res[4] = a1.x * m; res[5] = a1.y * m; res[6] = a1.z * m; res[7] = a1.w * m;
    }

    float* op = out + (size_t)elem * 24 + r * 8;   // 16B aligned
    float4 v0 = make_float4(res[0], res[1], res[2], res[3]);
    float4 v1 = make_float4(res[4], res[5], res[6], res[7]);
    *(float4*)(op) = v0;
    *(float4*)(op + 4) = v1;
}

// Fallback for is_tm=0 (out width 28). Not expected to be exercised by this
// setup (is_tm=1), but kept correct: one thread per element, scalar stores.
__global__ __launch_bounds__(256) void nottm_kernel(
    const float* __restrict__ info, const int* __restrict__ mask,
    const float* __restrict__ W, const float* __restrict__ bias,
    const float* __restrict__ emb1, const float* __restrict__ emb2,
    float* __restrict__ out, int n_elems)
{
    int elem = blockIdx.x * blockDim.x + threadIdx.x;
    if (elem >= n_elems) return;
    float m = (float)mask[elem];
    const float* ei = info + (size_t)elem * 7;
    float f[5];
    #pragma unroll
    for (int i = 0; i < 5; ++i) f[i] = ei[i] * m;
    float* op = out + (size_t)elem * 28;
    #pragma unroll
    for (int o = 0; o < 16; ++o) {
        float acc = bias[o];
        #pragma unroll
        for (int k = 0; k < 5; ++k) acc = fmaf(f[k], W[o * 5 + k], acc);
        op[o] = fmaxf(acc, 0.0f) * m;
    }
    int z = (int)(ei[5] * m);
    int idx = (z <= 0) ? 0 : ((z <= 20) ? z : ((z <= 38) ? z - 10 : z - 20));
    #pragma unroll
    for (int k = 0; k < 8; ++k) op[16 + k] = emb1[idx * 8 + k] * m;
    int t = (int)(ei[6] * m);
    #pragma unroll
    for (int k = 0; k < 4; ++k) op[24 + k] = emb2[t * 4 + k] * m;
}

extern "C" void kernel_launch(void* const* d_in, const int* in_sizes, int n_in,
                              void* d_out, int out_size, void* d_ws, size_t ws_size,
                              hipStream_t stream) {
    const float* info   = (const float*)d_in[0];   // (B,N,7) f32
    const int*   mask   = (const int*)d_in[1];     // (B,N) i32
    const float* W      = (const float*)d_in[2];   // (16,5)
    const float* bias   = (const float*)d_in[3];   // (16,)
    const float* TM_emb = (const float*)d_in[4];   // (21,8)
    const float* emb1   = (const float*)d_in[5];   // (75,8)
    const float* emb2   = (const float*)d_in[6];   // (6,4)
    // d_in[7] = is_tm scalar on device; branch inferred from output width.

    int n_elems = in_sizes[1];                     // B*N
    int width = out_size / n_elems;                // 24 (TM) or 28 (NotTM)
    float* out = (float*)d_out;

    if (width == 24) {
        long long threads = (long long)n_elems * 3;
        int blocks = (int)((threads + 255) / 256);
        tm_kernel<<<blocks, 256, 0, stream>>>(info, mask, W, bias, TM_emb, out, n_elems);
    } else {
        int blocks = (n_elems + 255) / 256;
        nottm_kernel<<<blocks, 256, 0, stream>>>(info, mask, W, bias, emb1, emb2, out, n_elems);
    }
}

// Round 2
// 263.991 us; speedup vs baseline: 1.1637x; 1.1637x over previous
//
#include <hip/hip_runtime.h>

// ElementsFeatureProcessor (TM path): B=16384, N=128, out width 24.
// out[e] = concat(relu(feat5[e] @ W^T + b)[16], TM_emb[map_tm(z[e])][8]) * mask[e]
//
// R2 design: one thread per element.
//  - W/bias indices wave-uniform (full unroll) -> s_load into SGPRs, matvec is pure VALU.
//  - No branch divergence: every thread does matvec + embedding gather.
//  - Writeout staged through LDS (pad 257) so global stores are contiguous
//    float4 per lane (1 KB/wave-instr) -- the proven ~6.5 TB/s store pattern.

__device__ __forceinline__ float4 f4scale(float4 a, float s) {
    return make_float4(a.x * s, a.y * s, a.z * s, a.w * s);
}

__global__ __launch_bounds__(256) void tm_kernel(
    const float* __restrict__ info, const int* __restrict__ mask,
    const float* __restrict__ W, const float* __restrict__ bias,
    const float* __restrict__ TM_emb, float* __restrict__ out, int n_elems)
{
    __shared__ float4 sOut[6 * 257];   // [c][t], pad 257 -> both phases conflict-free

    const int tid = threadIdx.x;
    const int elem = blockIdx.x * 256 + tid;

    if (elem < n_elems) {
        const float m = (float)mask[elem];          // 0.0 or 1.0
        const float* ei = info + (size_t)elem * 7;
        const float f0 = ei[0] * m, f1 = ei[1] * m, f2 = ei[2] * m,
                    f3 = ei[3] * m, f4 = ei[4] * m;

        float o[16];
        #pragma unroll
        for (int k = 0; k < 16; ++k) {
            // W, bias indices are uniform across lanes -> scalar loads (SGPRs)
            float acc = bias[k];
            acc = fmaf(f0, W[k * 5 + 0], acc);
            acc = fmaf(f1, W[k * 5 + 1], acc);
            acc = fmaf(f2, W[k * 5 + 2], acc);
            acc = fmaf(f3, W[k * 5 + 3], acc);
            acc = fmaf(f4, W[k * 5 + 4], acc);
            o[k] = fmaxf(acc, 0.0f) * m;
        }
        sOut[0 * 257 + tid] = make_float4(o[0],  o[1],  o[2],  o[3]);
        sOut[1 * 257 + tid] = make_float4(o[4],  o[5],  o[6],  o[7]);
        sOut[2 * 257 + tid] = make_float4(o[8],  o[9],  o[10], o[11]);
        sOut[3 * 257 + tid] = make_float4(o[12], o[13], o[14], o[15]);

        // masked z is exact in fp32 (z <= 48); map_tm on masked z
        const int z = (int)(ei[5] * m);
        const int idx = (z <= 0) ? 0 : ((z <= 30) ? z - 20 : z - 28);
        const float4* e4 = (const float4*)(TM_emb + (size_t)idx * 8);  // rows 32B-aligned
        sOut[4 * 257 + tid] = f4scale(e4[0], m);
        sOut[5 * 257 + tid] = f4scale(e4[1], m);
    }
    __syncthreads();

    // Coalesced writeout: 1536 float4 = 256 elems x 96 B, contiguous.
    float4* out4 = (float4*)out + (size_t)blockIdx.x * 1536;
    const int elem0 = blockIdx.x * 256;
    #pragma unroll
    for (int it = 0; it < 6; ++it) {
        const unsigned int g = it * 256 + tid;      // 0..1535
        const unsigned int e = g / 6u;              // local element
        const unsigned int c = g - e * 6u;          // chunk 0..5
        if (elem0 + (int)e < n_elems)
            out4[g] = sOut[c * 257 + e];
    }
}

// Fallback for is_tm=0 (out width 28). Not exercised by this setup.
__global__ __launch_bounds__(256) void nottm_kernel(
    const float* __restrict__ info, const int* __restrict__ mask,
    const float* __restrict__ W, const float* __restrict__ bias,
    const float* __restrict__ emb1, const float* __restrict__ emb2,
    float* __restrict__ out, int n_elems)
{
    int elem = blockIdx.x * blockDim.x + threadIdx.x;
    if (elem >= n_elems) return;
    float m = (float)mask[elem];
    const float* ei = info + (size_t)elem * 7;
    float f[5];
    #pragma unroll
    for (int i = 0; i < 5; ++i) f[i] = ei[i] * m;
    float* op = out + (size_t)elem * 28;
    #pragma unroll
    for (int o = 0; o < 16; ++o) {
        float acc = bias[o];
        #pragma unroll
        for (int k = 0; k < 5; ++k) acc = fmaf(f[k], W[o * 5 + k], acc);
        op[o] = fmaxf(acc, 0.0f) * m;
    }
    int z = (int)(ei[5] * m);
    int idx = (z <= 0) ? 0 : ((z <= 20) ? z : ((z <= 38) ? z - 10 : z - 20));
    #pragma unroll
    for (int k = 0; k < 8; ++k) op[16 + k] = emb1[idx * 8 + k] * m;
    int t = (int)(ei[6] * m);
    #pragma unroll
    for (int k = 0; k < 4; ++k) op[24 + k] = emb2[t * 4 + k] * m;
}

extern "C" void kernel_launch(void* const* d_in, const int* in_sizes, int n_in,
                              void* d_out, int out_size, void* d_ws, size_t ws_size,
                              hipStream_t stream) {
    const float* info   = (const float*)d_in[0];   // (B,N,7) f32
    const int*   mask   = (const int*)d_in[1];     // (B,N) i32
    const float* W      = (const float*)d_in[2];   // (16,5)
    const float* bias   = (const float*)d_in[3];   // (16,)
    const float* TM_emb = (const float*)d_in[4];   // (21,8)
    const float* emb1   = (const float*)d_in[5];   // (75,8)
    const float* emb2   = (const float*)d_in[6];   // (6,4)

    int n_elems = in_sizes[1];                     // B*N
    int width = out_size / n_elems;                // 24 (TM) or 28 (NotTM)
    float* out = (float*)d_out;

    if (width == 24) {
        int blocks = (n_elems + 255) / 256;        // 8192 for B=16384,N=128
        tm_kernel<<<blocks, 256, 0, stream>>>(info, mask, W, bias, TM_emb, out, n_elems);
    } else {
        int blocks = (n_elems + 255) / 256;
        nottm_kernel<<<blocks, 256, 0, stream>>>(info, mask, W, bias, emb1, emb2, out, n_elems);
    }
}

// Round 3
// 261.240 us; speedup vs baseline: 1.1760x; 1.0105x over previous
//
#include <hip/hip_runtime.h>

// ElementsFeatureProcessor (TM path): B=16384, N=128, out width 24.
// out[e] = concat(relu(feat5[e] @ W^T + b)[16], TM_emb[map_tm(z[e])][8]) * mask[e]
//
// R3 design: one thread per element, LDS-staged on BOTH sides.
//  - Read: block's info slice = exactly 448 contiguous float4 (256 elems x 28 B)
//    loaded dense into LDS (1 KB/wave-instr), then per-thread stride-7 float
//    reads from LDS (odd stride -> conflict-free, 2 lanes/bank is free).
//  - Matvec: W/bias wave-uniform -> SGPR scalar loads, pure VALU FMAs.
//  - Write: staged via sOut (pad 257), then 6 contiguous float4 wave-stores
//    per block (the proven ~6.5 TB/s pattern).

__device__ __forceinline__ float4 f4scale(float4 a, float s) {
    return make_float4(a.x * s, a.y * s, a.z * s, a.w * s);
}

__global__ __launch_bounds__(256) void tm_kernel(
    const float* __restrict__ info, const int* __restrict__ mask,
    const float* __restrict__ W, const float* __restrict__ bias,
    const float* __restrict__ TM_emb, float* __restrict__ out, int n_elems)
{
    __shared__ float4 sIn4[448];       // 7168 B: 256 elems x 7 floats
    __shared__ float4 sOut[6 * 257];   // 24672 B: write-contiguous, pad 257

    const int tid = threadIdx.x;
    const long long elem0 = (long long)blockIdx.x * 256;
    const bool full = (elem0 + 256 <= (long long)n_elems);

    if (full) {
        // dense, exact-fit staging: blk*448 float4s, always 16B-aligned
        const float4* g4 = (const float4*)info + (size_t)blockIdx.x * 448;
        sIn4[tid] = g4[tid];
        if (tid < 192) sIn4[256 + tid] = g4[256 + tid];
    }
    __syncthreads();

    const int elem = (int)elem0 + tid;
    if (elem < n_elems) {
        float e0, e1, e2, e3, e4, e5;
        if (full) {
            const float* si = (const float*)sIn4 + tid * 7;  // stride 7: conflict-free
            e0 = si[0]; e1 = si[1]; e2 = si[2];
            e3 = si[3]; e4 = si[4]; e5 = si[5];
        } else {
            const float* gi = info + (size_t)elem * 7;       // rare tail block
            e0 = gi[0]; e1 = gi[1]; e2 = gi[2];
            e3 = gi[3]; e4 = gi[4]; e5 = gi[5];
        }
        const float m = (float)mask[elem];                   // dense dword load
        const float f0 = e0 * m, f1 = e1 * m, f2 = e2 * m,
                    f3 = e3 * m, f4 = e4 * m;

        float o[16];
        #pragma unroll
        for (int k = 0; k < 16; ++k) {
            // uniform indices -> s_load into SGPRs
            float acc = bias[k];
            acc = fmaf(f0, W[k * 5 + 0], acc);
            acc = fmaf(f1, W[k * 5 + 1], acc);
            acc = fmaf(f2, W[k * 5 + 2], acc);
            acc = fmaf(f3, W[k * 5 + 3], acc);
            acc = fmaf(f4, W[k * 5 + 4], acc);
            o[k] = fmaxf(acc, 0.0f) * m;
        }
        sOut[0 * 257 + tid] = make_float4(o[0],  o[1],  o[2],  o[3]);
        sOut[1 * 257 + tid] = make_float4(o[4],  o[5],  o[6],  o[7]);
        sOut[2 * 257 + tid] = make_float4(o[8],  o[9],  o[10], o[11]);
        sOut[3 * 257 + tid] = make_float4(o[12], o[13], o[14], o[15]);

        // masked z exact in fp32 (z <= 48); map_tm(z): {0}->0, 21..30->1..10, 39..48->11..20
        const int z = (int)(e5 * m);
        const int idx = (z <= 0) ? 0 : ((z <= 30) ? z - 20 : z - 28);
        const float4* t4 = (const float4*)(TM_emb + (size_t)idx * 8);  // 32B-aligned rows
        sOut[4 * 257 + tid] = f4scale(t4[0], m);
        sOut[5 * 257 + tid] = f4scale(t4[1], m);
    }
    __syncthreads();

    // Coalesced writeout: 1536 contiguous float4 per block (96 B x 256 elems).
    float4* out4 = (float4*)out + (size_t)blockIdx.x * 1536;
    #pragma unroll
    for (int it = 0; it < 6; ++it) {
        const unsigned int g = it * 256 + tid;       // 0..1535, wave-contiguous
        const unsigned int e = g / 6u;               // local element
        const unsigned int c = g - e * 6u;           // chunk 0..5
        if (elem0 + (long long)e < (long long)n_elems)
            out4[g] = sOut[c * 257 + e];
    }
}

// Fallback for is_tm=0 (out width 28). Not exercised by this setup.
__global__ __launch_bounds__(256) void nottm_kernel(
    const float* __restrict__ info, const int* __restrict__ mask,
    const float* __restrict__ W, const float* __restrict__ bias,
    const float* __restrict__ emb1, const float* __restrict__ emb2,
    float* __restrict__ out, int n_elems)
{
    int elem = blockIdx.x * blockDim.x + threadIdx.x;
    if (elem >= n_elems) return;
    float m = (float)mask[elem];
    const float* ei = info + (size_t)elem * 7;
    float f[5];
    #pragma unroll
    for (int i = 0; i < 5; ++i) f[i] = ei[i] * m;
    float* op = out + (size_t)elem * 28;
    #pragma unroll
    for (int o = 0; o < 16; ++o) {
        float acc = bias[o];
        #pragma unroll
        for (int k = 0; k < 5; ++k) acc = fmaf(f[k], W[o * 5 + k], acc);
        op[o] = fmaxf(acc, 0.0f) * m;
    }
    int z = (int)(ei[5] * m);
    int idx = (z <= 0) ? 0 : ((z <= 20) ? z : ((z <= 38) ? z - 10 : z - 20));
    #pragma unroll
    for (int k = 0; k < 8; ++k) op[16 + k] = emb1[idx * 8 + k] * m;
    int t = (int)(ei[6] * m);
    #pragma unroll
    for (int k = 0; k < 4; ++k) op[24 + k] = emb2[t * 4 + k] * m;
}

extern "C" void kernel_launch(void* const* d_in, const int* in_sizes, int n_in,
                              void* d_out, int out_size, void* d_ws, size_t ws_size,
                              hipStream_t stream) {
    const float* info   = (const float*)d_in[0];   // (B,N,7) f32
    const int*   mask   = (const int*)d_in[1];     // (B,N) i32
    const float* W      = (const float*)d_in[2];   // (16,5)
    const float* bias   = (const float*)d_in[3];   // (16,)
    const float* TM_emb = (const float*)d_in[4];   // (21,8)
    const float* emb1   = (const float*)d_in[5];   // (75,8)
    const float* emb2   = (const float*)d_in[6];   // (6,4)

    int n_elems = in_sizes[1];                     // B*N
    int width = out_size / n_elems;                // 24 (TM) or 28 (NotTM)
    float* out = (float*)d_out;

    if (width == 24) {
        int blocks = (n_elems + 255) / 256;        // 8192 for B=16384,N=128
        tm_kernel<<<blocks, 256, 0, stream>>>(info, mask, W, bias, TM_emb, out, n_elems);
    } else {
        int blocks = (n_elems + 255) / 256;
        nottm_kernel<<<blocks, 256, 0, stream>>>(info, mask, W, bias, emb1, emb2, out, n_elems);
    }
}

// Round 5
// 258.256 us; speedup vs baseline: 1.1896x; 1.0116x over previous
//
#include <hip/hip_runtime.h>

// ElementsFeatureProcessor (TM path): B=16384, N=128, out width 24.
// out[e] = concat(relu(feat5[e] @ W^T + b)[16], TM_emb[map_tm(z[e])][8]) * mask[e]
//
// R5 = R4 with the nontemporal-store type fixed (clang ext_vector_type).
// SINGLE-WAVE workgroups (64 threads), one wave per block:
//  - no cross-wave barrier coupling; ~16 independent waves/CU free-run
//    their load -> LDS -> compute -> LDS -> store pipelines.
//  - Read: 112 contiguous float4 per block staged dense into LDS;
//    per-thread stride-7 reads (odd stride, conflict-free).
//  - Matvec: W/bias wave-uniform -> SGPR s_loads, pure VALU.
//  - Write: LDS transpose (pad 65) then 6 contiguous 16B wave-stores,
//    nontemporal (201 MB streamed, never re-read).

typedef float fx4 __attribute__((ext_vector_type(4)));

__device__ __forceinline__ fx4 f4scale(fx4 a, float s) { return a * s; }

__global__ __launch_bounds__(64) void tm_kernel(
    const float* __restrict__ info, const int* __restrict__ mask,
    const float* __restrict__ W, const float* __restrict__ bias,
    const float* __restrict__ TM_emb, float* __restrict__ out, int n_elems)
{
    __shared__ fx4 sIn4[112];      // 1792 B: 64 elems x 7 floats
    __shared__ fx4 sOut[6 * 65];   // 6240 B: write-contiguous, pad 65

    const int tid = threadIdx.x;      // 0..63
    const long long elem0 = (long long)blockIdx.x * 64;
    const bool full = (elem0 + 64 <= (long long)n_elems);
    const int elem = (int)elem0 + tid;

    if (full) {
        const fx4* g4 = (const fx4*)info + (size_t)blockIdx.x * 112;
        sIn4[tid] = g4[tid];
        if (tid < 48) sIn4[64 + tid] = g4[64 + tid];
    }
    __syncthreads();   // single-wave: cheap

    if (elem < n_elems) {
        float e0, e1, e2, e3, e4, e5;
        if (full) {
            const float* si = (const float*)sIn4 + tid * 7;  // stride 7: conflict-free
            e0 = si[0]; e1 = si[1]; e2 = si[2];
            e3 = si[3]; e4 = si[4]; e5 = si[5];
        } else {
            const float* gi = info + (size_t)elem * 7;       // tail (n % 64 == 0: unused)
            e0 = gi[0]; e1 = gi[1]; e2 = gi[2];
            e3 = gi[3]; e4 = gi[4]; e5 = gi[5];
        }
        const float m = (float)mask[elem];
        const float f0 = e0 * m, f1 = e1 * m, f2 = e2 * m,
                    f3 = e3 * m, f4 = e4 * m;

        float o[16];
        #pragma unroll
        for (int k = 0; k < 16; ++k) {
            // uniform indices -> SGPR scalar loads
            float acc = bias[k];
            acc = fmaf(f0, W[k * 5 + 0], acc);
            acc = fmaf(f1, W[k * 5 + 1], acc);
            acc = fmaf(f2, W[k * 5 + 2], acc);
            acc = fmaf(f3, W[k * 5 + 3], acc);
            acc = fmaf(f4, W[k * 5 + 4], acc);
            o[k] = fmaxf(acc, 0.0f) * m;
        }
        sOut[0 * 65 + tid] = (fx4){o[0],  o[1],  o[2],  o[3]};
        sOut[1 * 65 + tid] = (fx4){o[4],  o[5],  o[6],  o[7]};
        sOut[2 * 65 + tid] = (fx4){o[8],  o[9],  o[10], o[11]};
        sOut[3 * 65 + tid] = (fx4){o[12], o[13], o[14], o[15]};

        // masked z exact in fp32 (z <= 48); map_tm: 0->0, 21..30->z-20, 39..48->z-28
        const int z = (int)(e5 * m);
        const int idx = (z <= 0) ? 0 : ((z <= 30) ? z - 20 : z - 28);
        const fx4* t4 = (const fx4*)(TM_emb + (size_t)idx * 8);  // 32B-aligned rows
        sOut[4 * 65 + tid] = f4scale(t4[0], m);
        sOut[5 * 65 + tid] = f4scale(t4[1], m);
    }
    __syncthreads();

    // Coalesced nontemporal writeout: 384 contiguous 16B stores per block.
    fx4* out4 = (fx4*)out + (size_t)blockIdx.x * 384;
    #pragma unroll
    for (int it = 0; it < 6; ++it) {
        const unsigned int g = it * 64 + tid;        // 0..383, wave-contiguous
        const unsigned int e = g / 6u;               // local element
        const unsigned int c = g - e * 6u;           // chunk 0..5
        if (elem0 + (long long)e < (long long)n_elems)
            __builtin_nontemporal_store(sOut[c * 65 + e], &out4[g]);
    }
}

// Fallback for is_tm=0 (out width 28). Not exercised by this setup.
__global__ __launch_bounds__(256) void nottm_kernel(
    const float* __restrict__ info, const int* __restrict__ mask,
    const float* __restrict__ W, const float* __restrict__ bias,
    const float* __restrict__ emb1, const float* __restrict__ emb2,
    float* __restrict__ out, int n_elems)
{
    int elem = blockIdx.x * blockDim.x + threadIdx.x;
    if (elem >= n_elems) return;
    float m = (float)mask[elem];
    const float* ei = info + (size_t)elem * 7;
    float f[5];
    #pragma unroll
    for (int i = 0; i < 5; ++i) f[i] = ei[i] * m;
    float* op = out + (size_t)elem * 28;
    #pragma unroll
    for (int o = 0; o < 16; ++o) {
        float acc = bias[o];
        #pragma unroll
        for (int k = 0; k < 5; ++k) acc = fmaf(f[k], W[o * 5 + k], acc);
        op[o] = fmaxf(acc, 0.0f) * m;
    }
    int z = (int)(ei[5] * m);
    int idx = (z <= 0) ? 0 : ((z <= 20) ? z : ((z <= 38) ? z - 10 : z - 20));
    #pragma unroll
    for (int k = 0; k < 8; ++k) op[16 + k] = emb1[idx * 8 + k] * m;
    int t = (int)(ei[6] * m);
    #pragma unroll
    for (int k = 0; k < 4; ++k) op[24 + k] = emb2[t * 4 + k] * m;
}

extern "C" void kernel_launch(void* const* d_in, const int* in_sizes, int n_in,
                              void* d_out, int out_size, void* d_ws, size_t ws_size,
                              hipStream_t stream) {
    const float* info   = (const float*)d_in[0];   // (B,N,7) f32
    const int*   mask   = (const int*)d_in[1];     // (B,N) i32
    const float* W      = (const float*)d_in[2];   // (16,5)
    const float* bias   = (const float*)d_in[3];   // (16,)
    const float* TM_emb = (const float*)d_in[4];   // (21,8)
    const float* emb1   = (const float*)d_in[5];   // (75,8)
    const float* emb2   = (const float*)d_in[6];   // (6,4)

    int n_elems = in_sizes[1];                     // B*N
    int width = out_size / n_elems;                // 24 (TM) or 28 (NotTM)
    float* out = (float*)d_out;

    if (width == 24) {
        int blocks = (n_elems + 63) / 64;          // 32768 single-wave blocks
        tm_kernel<<<blocks, 64, 0, stream>>>(info, mask, W, bias, TM_emb, out, n_elems);
    } else {
        int blocks = (n_elems + 255) / 256;
        nottm_kernel<<<blocks, 256, 0, stream>>>(info, mask, W, bias, emb1, emb2, out, n_elems);
    }
}